// Round 5
// baseline (315.036 us; speedup 1.0000x reference)
//
#include <hip/hip_runtime.h>
#include <hip/hip_bf16.h>
#include <hip/hip_cooperative_groups.h>

namespace cg = cooperative_groups;

// LOIMLoss on MI355X (gfx950) — R17: single cooperative mega-kernel.
// R16 FAILED (79us): 8 waves x 32 rows doubled LDS reads/MFMA -> LDS-BW-bound
// (conflicts 7.1M, MfmaUtil 29.5). M=64/wave (R14) is the right ratio; R14
// gemm body (62us, MfmaUtil 36.9) is FROZEN below, used verbatim in both the
// mega kernel (phase 1) and the fallback path.
// R17 theory: total 172us - 62 gemm - ~25 preprocess - ~5 focal => ~70-80us
// of inter-kernel serialization. Fuse everything into ONE cooperative kernel
// (512 blocks x 256 thr = 2 blocks/CU co-resident): phase0 convert ->
// grid.sync -> phase1 R14 gemm -> grid.sync -> phase2 focal + ticketed loss.
// Host falls back to the proven 3-kernel path if cooperative launch errors.
//
// Output model (R11, absmax 0.0): d_out f32[out]; [0]=loss, [1..524289)=inputs
// copy, [524289..)=label bf16-RNE upcast. d_in[0..2] f32.

#define NFEAT 256
#define NROIS 2048
#define NPIDS 5554
#define NCLS 55554            // NPIDS + 50000
#define NCHUNKS 3473          // ceil(NCLS/16)  (non-TB fallback granularity)
#define NCH32 1737            // ceil(NCLS/32)  (TB path granularity)
#define NCLSP (NCH32 * 32)    // 55584: rows [NCLS..NCLSP) zeroed in tb
#define S2F 43.280851226668906f   // 30 * log2(e)
#define LN2F 0.6931471805599453f
#define LOFF 524289

typedef float f32x4 __attribute__((ext_vector_type(4)));
typedef short bf16x8 __attribute__((ext_vector_type(8)));
typedef unsigned short u16x8 __attribute__((ext_vector_type(8)));

#if __has_builtin(__builtin_amdgcn_exp2f)
#define EXP2(x) __builtin_amdgcn_exp2f(x)
#else
#define EXP2(x) exp2f(x)
#endif

__device__ __forceinline__ short bfb(float x) {
    return __builtin_bit_cast(short, __float2bfloat16(x));   // RNE
}

// 16B global->LDS direct (dest = wave-uniform base + lane*16, src per-lane).
__device__ __forceinline__ void gll16(const void* g, void* l) {
    __builtin_amdgcn_global_load_lds(
        (const __attribute__((address_space(1))) void*)g,
        (__attribute__((address_space(3))) void*)l, 16, 0, 0);
}

// ============================ MEGA (cooperative) ============================
// grid MUST be 512 x 256 (2 blocks/CU co-resident; hipLaunchCooperativeKernel
// validates). LDS 48KB, launch_bounds(256,2) caps regs at 256/wave.
__global__ __launch_bounds__(256, 2) void mega(
        const float* __restrict__ inputs, const float* __restrict__ lut,
        const float* __restrict__ cq, const int* __restrict__ cand0,
        const int* __restrict__ cand1, unsigned short* __restrict__ tb,
        unsigned short* __restrict__ ab, int* __restrict__ lab,
        float* __restrict__ S, float* __restrict__ loss_acc,
        unsigned int* __restrict__ cnt, float* __restrict__ f) {
    __shared__ short ldsb[3][8192];               // 3 x 16 KB (phase 1)
    const int tid = threadIdx.x;
    const int bx = blockIdx.x;
    const int lane = tid & 63;
    const int wave = tid >> 6;

    // ---------------- phase 0: prep + conversions ----------------
    if (bx == 0) {
        __shared__ int smode;
        __shared__ const int* sT;
        if (tid == 0) {
            const int* T = cand0;
            const unsigned u0 = (unsigned)cand0[0];
            const float f0 = __builtin_bit_cast(float, cand0[0]);
            const bool oki = (u0 >= 1u && u0 <= 6000u);
            const bool okf = (f0 >= 1.0f && f0 <= 6000.0f);
            if (!oki && !okf) T = cand1;
            int mode = 0;                          // 0=int32, 1=int64(LE), 2=f32
            const unsigned tu0 = (unsigned)T[0];
            const float tf0 = __builtin_bit_cast(float, T[0]);
            if (tu0 >= 1u && tu0 <= 6000u) mode = ((T[1] | T[3] | T[5] | T[7]) == 0) ? 1 : 0;
            else if (tf0 >= 1.0f && tf0 <= 6000.0f) mode = 2;
            smode = mode; sT = T;
        }
        __syncthreads();
        const int mode = smode;
        const int* T = sT;
        for (int j = tid; j < NROIS; j += 256) {
            int tv;
            if (mode == 1)      tv = T[2 * j];
            else if (mode == 2) tv = (int)__builtin_bit_cast(float, T[j]);
            else                tv = T[j];
            const int lv = tv - 1;
            lab[j] = lv;
            f[LOFF + j] = __bfloat162float(__float2bfloat16((float)lv));
        }
        for (int j = tid; j < NROIS + 8; j += 256) S[j] = 0.0f;  // S, loss, cnt
    }
    {   // inputs copy -> f[1..] and bf16 A (one float4 unit per thread)
        const int i = bx * 256 + tid;             // 131072 units
        const float4 v = *reinterpret_cast<const float4*>(inputs + (size_t)i * 4);
        float* o = f + 1 + (size_t)i * 4;         // f+1 unaligned: scalar stores
        o[0] = v.x; o[1] = v.y; o[2] = v.z; o[3] = v.w;
        ushort4 u;
        u.x = (unsigned short)bfb(v.x); u.y = (unsigned short)bfb(v.y);
        u.z = (unsigned short)bfb(v.z); u.w = (unsigned short)bfb(v.w);
        *reinterpret_cast<ushort4*>(ab + (size_t)i * 4) = u;
    }
    {   // fp32 [lut;cq] -> bf16 tb, rows [NCLS..NCLSP) = 0 (grid-stride)
        const size_t LUTN = (size_t)NPIDS * NFEAT;
        const size_t TOT  = (size_t)NCLS * NFEAT;
        const size_t TOTP = (size_t)NCLSP * NFEAT;
        const size_t stride = (size_t)gridDim.x * 256 * 8;
        for (size_t e = ((size_t)bx * 256 + tid) * 8; e < TOTP; e += stride) {
            u16x8 o = {0, 0, 0, 0, 0, 0, 0, 0};
            if (e < TOT) {
                const float* sp = (e < LUTN) ? (lut + e) : (cq + (e - LUTN));
                const float4 a = *reinterpret_cast<const float4*>(sp);
                const float4 b = *reinterpret_cast<const float4*>(sp + 4);
                o[0] = (unsigned short)bfb(a.x); o[1] = (unsigned short)bfb(a.y);
                o[2] = (unsigned short)bfb(a.z); o[3] = (unsigned short)bfb(a.w);
                o[4] = (unsigned short)bfb(b.x); o[5] = (unsigned short)bfb(b.y);
                o[6] = (unsigned short)bfb(b.z); o[7] = (unsigned short)bfb(b.w);
            }
            *reinterpret_cast<u16x8*>(tb + e) = o;
        }
    }
    cg::this_grid().sync();

    // ---------------- phase 1: R14 gemm body (FROZEN) ----------------
    {
        const int cs = bx & 63;
        const int rg = bx >> 6;
        const int rowbase = rg * 256 + wave * 64;
        const int li = lane & 15;
        const int q = lane >> 4;
        const int xorli = 4 * (li & 7);
        char* const lbase = (char*)&ldsb[0][0];

        bf16x8 afrag[4][8];
        #pragma unroll
        for (int s = 0; s < 4; s++) {
            const unsigned short* rp = ab + (size_t)(rowbase + s * 16 + li) * NFEAT + q * 8;
            #pragma unroll
            for (int kc = 0; kc < 8; kc++)
                afrag[s][kc] = *reinterpret_cast<const bf16x8*>(rp + kc * 32);
        }

        float sums[4][4] = {{0.f,0.f,0.f,0.f},{0.f,0.f,0.f,0.f},
                            {0.f,0.f,0.f,0.f},{0.f,0.f,0.f,0.f}};

        const int cc0 = tid >> 5;
        const int uo = ((tid & 31) ^ (4 * (cc0 & 7))) * 8;
        const int ldd = wave * 1024;             // + k*4096, HW adds lane*16
        const int cA = (cs * NCH32) >> 6;
        const int cB = ((cs + 1) * NCH32) >> 6;
        const int NB = cB - cA;
        const unsigned short* psrc = tb + (size_t)(cA * 32 + cc0) * NFEAT + uo;
        int ob0 = 0, ob1 = 16384, ob2 = 32768;

        #pragma unroll
        for (int k = 0; k < 4; k++)
            gll16(psrc + (size_t)(8 * k) * NFEAT, lbase + ob0 + ldd + k * 4096);
        psrc += (size_t)32 * NFEAT;
        if (NB > 1) {
            #pragma unroll
            for (int k = 0; k < 4; k++)
                gll16(psrc + (size_t)(8 * k) * NFEAT, lbase + ob1 + ldd + k * 4096);
            psrc += (size_t)32 * NFEAT;
        }

        for (int i = 0; i < NB; ++i) {
            if (i + 1 < NB) asm volatile("s_waitcnt vmcnt(4)\n\ts_barrier" ::: "memory");
            else            asm volatile("s_waitcnt vmcnt(0)\n\ts_barrier" ::: "memory");
            if (i + 2 < NB) {
                #pragma unroll
                for (int k = 0; k < 4; k++)
                    gll16(psrc + (size_t)(8 * k) * NFEAT, lbase + ob2 + ldd + k * 4096);
                psrc += (size_t)32 * NFEAT;
            }
            #pragma unroll
            for (int h = 0; h < 2; h++) {        // two 16-class sub-chunks
                const int cc = h * 16 + li;
                bf16x8 bfr[8];
                #pragma unroll
                for (int kc = 0; kc < 8; kc++) {
                    const int slot = cc * 32 + ((q + 4 * kc) ^ xorli);
                    bfr[kc] = *reinterpret_cast<const bf16x8*>(lbase + ob0 + slot * 16);
                }
                f32x4 acc[4] = {{0.f,0.f,0.f,0.f},{0.f,0.f,0.f,0.f},
                                {0.f,0.f,0.f,0.f},{0.f,0.f,0.f,0.f}};
                __builtin_amdgcn_s_setprio(1);
                #pragma unroll
                for (int kc = 0; kc < 8; kc++) {
                    acc[0] = __builtin_amdgcn_mfma_f32_16x16x32_bf16(afrag[0][kc], bfr[kc], acc[0], 0, 0, 0);
                    acc[1] = __builtin_amdgcn_mfma_f32_16x16x32_bf16(afrag[1][kc], bfr[kc], acc[1], 0, 0, 0);
                    acc[2] = __builtin_amdgcn_mfma_f32_16x16x32_bf16(afrag[2][kc], bfr[kc], acc[2], 0, 0, 0);
                    acc[3] = __builtin_amdgcn_mfma_f32_16x16x32_bf16(afrag[3][kc], bfr[kc], acc[3], 0, 0, 0);
                }
                __builtin_amdgcn_s_setprio(0);
                #pragma unroll
                for (int s = 0; s < 4; s++)
                    #pragma unroll
                    for (int r = 0; r < 4; r++)
                        sums[s][r] += EXP2(S2F * acc[s][r] - S2F);
            }
            const int t = ob0; ob0 = ob1; ob1 = ob2; ob2 = t;
        }

        #pragma unroll
        for (int s = 0; s < 4; s++)
            #pragma unroll
            for (int r = 0; r < 4; r++) {
                float v = sums[s][r];
                v += __shfl_xor(v, 1); v += __shfl_xor(v, 2);
                v += __shfl_xor(v, 4); v += __shfl_xor(v, 8);
                sums[s][r] = v;
            }
        if (li == 0) {
            #pragma unroll
            for (int s = 0; s < 4; s++)
                #pragma unroll
                for (int r = 0; r < 4; r++)
                    atomicAdd(&S[rowbase + s * 16 + q * 4 + r], sums[s][r]);
        }
    }
    cg::this_grid().sync();

    // ---------------- phase 2: focal + ticketed loss write ----------------
    {
        const int row = bx * 4 + wave;
        const int label = lab[row];
        const bool valid = (label >= 0 && label < NPIDS);
        const int lr = valid ? label : 0;
        const float4 a = *reinterpret_cast<const float4*>(inputs + (size_t)row * NFEAT + lane * 4);
        const float4 b = *reinterpret_cast<const float4*>(lut + (size_t)lr * NFEAT + lane * 4);
        float v = a.x * b.x + a.y * b.y + a.z * b.z + a.w * b.w;
        #pragma unroll
        for (int m = 1; m < 64; m <<= 1) v += __shfl_xor(v, m);

        __shared__ float red[4];
        if (lane == 0) {
            float fo = 0.0f;
            if (valid) {
                const float l2 = v * S2F;
                const float lse2 = S2F + log2f(S[row]);
                float ce = fmaxf((lse2 - l2) * LN2F, 0.0f);
                const float pt = EXP2(l2 - lse2);
                const float om = 1.0f - pt;
                fo = om * om * ce;
            }
            red[wave] = fo;
        }
        __syncthreads();
        if (tid == 0) {
            atomicAdd(loss_acc, red[0] + red[1] + red[2] + red[3]);
            __threadfence();
            const unsigned done = atomicAdd(cnt, 1u) + 1u;
            if (done == gridDim.x) {
                const float tot = atomicAdd(loss_acc, 0.0f);  // coherent read
                f[0] = tot * (1.0f / NROIS);
            }
        }
    }
}

// ===================== fallback: R14 3-kernel path (proven) =================

__global__ __launch_bounds__(256) void preprocess(
        const float* __restrict__ inputs, const float* __restrict__ lut,
        const float* __restrict__ cq, const int* __restrict__ cand0,
        const int* __restrict__ cand1, unsigned short* __restrict__ tb,
        unsigned short* __restrict__ ab, int* __restrict__ lab,
        float* __restrict__ S, float* __restrict__ f, const int useTB) {
    const int tid = threadIdx.x;
    const int bx = blockIdx.x;
    if (bx == 0) {
        __shared__ int smode;
        __shared__ const int* sT;
        if (tid == 0) {
            const int* T = cand0;
            const unsigned u0 = (unsigned)cand0[0];
            const float f0 = __builtin_bit_cast(float, cand0[0]);
            const bool oki = (u0 >= 1u && u0 <= 6000u);
            const bool okf = (f0 >= 1.0f && f0 <= 6000.0f);
            if (!oki && !okf) T = cand1;
            int mode = 0;
            const unsigned tu0 = (unsigned)T[0];
            const float tf0 = __builtin_bit_cast(float, T[0]);
            if (tu0 >= 1u && tu0 <= 6000u) mode = ((T[1] | T[3] | T[5] | T[7]) == 0) ? 1 : 0;
            else if (tf0 >= 1.0f && tf0 <= 6000.0f) mode = 2;
            smode = mode; sT = T;
        }
        __syncthreads();
        const int mode = smode;
        const int* T = sT;
        for (int j = tid; j < NROIS; j += 256) {
            int tv;
            if (mode == 1)      tv = T[2 * j];
            else if (mode == 2) tv = (int)__builtin_bit_cast(float, T[j]);
            else                tv = T[j];
            const int lv = tv - 1;
            lab[j] = lv;
            f[LOFF + j] = __bfloat162float(__float2bfloat16((float)lv));
        }
        for (int j = tid; j < NROIS + 8; j += 256) S[j] = 0.0f;
    }
    if (bx < 512) {
        const int i = bx * 256 + tid;
        const float4 v = *reinterpret_cast<const float4*>(inputs + (size_t)i * 4);
        float* o = f + 1 + (size_t)i * 4;
        o[0] = v.x; o[1] = v.y; o[2] = v.z; o[3] = v.w;
        if (useTB) {
            ushort4 u;
            u.x = (unsigned short)bfb(v.x); u.y = (unsigned short)bfb(v.y);
            u.z = (unsigned short)bfb(v.z); u.w = (unsigned short)bfb(v.w);
            *reinterpret_cast<ushort4*>(ab + (size_t)i * 4) = u;
        }
    }
    if (useTB) {
        const size_t LUTN = (size_t)NPIDS * NFEAT;
        const size_t TOT  = (size_t)NCLS * NFEAT;
        const size_t TOTP = (size_t)NCLSP * NFEAT;
        const size_t stride = (size_t)gridDim.x * 256 * 8;
        for (size_t e = ((size_t)bx * 256 + tid) * 8; e < TOTP; e += stride) {
            u16x8 o = {0, 0, 0, 0, 0, 0, 0, 0};
            if (e < TOT) {
                const float* sp = (e < LUTN) ? (lut + e) : (cq + (e - LUTN));
                const float4 a = *reinterpret_cast<const float4*>(sp);
                const float4 b = *reinterpret_cast<const float4*>(sp + 4);
                o[0] = (unsigned short)bfb(a.x); o[1] = (unsigned short)bfb(a.y);
                o[2] = (unsigned short)bfb(a.z); o[3] = (unsigned short)bfb(a.w);
                o[4] = (unsigned short)bfb(b.x); o[5] = (unsigned short)bfb(b.y);
                o[6] = (unsigned short)bfb(b.z); o[7] = (unsigned short)bfb(b.w);
            }
            *reinterpret_cast<u16x8*>(tb + e) = o;
        }
    }
}

template <bool TB>
__global__ __launch_bounds__(256, 2) void main_gemm4(const float* __restrict__ inputs,
                                                     const unsigned short* __restrict__ tb,
                                                     const unsigned short* __restrict__ ab,
                                                     const float* __restrict__ lut,
                                                     const float* __restrict__ cq,
                                                     float* __restrict__ S) {
    __shared__ short ldsb[3][8192];
    const int tid = threadIdx.x;
    const int lane = tid & 63;
    const int wave = tid >> 6;
    const int cs = blockIdx.x & 63;
    const int rg = blockIdx.x >> 6;
    const int rowbase = rg * 256 + wave * 64;
    const int li = lane & 15;
    const int q = lane >> 4;
    const int xorli = 4 * (li & 7);

    bf16x8 afrag[4][8];
    if constexpr (TB) {
        #pragma unroll
        for (int s = 0; s < 4; s++) {
            const unsigned short* rp = ab + (size_t)(rowbase + s * 16 + li) * NFEAT + q * 8;
            #pragma unroll
            for (int kc = 0; kc < 8; kc++)
                afrag[s][kc] = *reinterpret_cast<const bf16x8*>(rp + kc * 32);
        }
    } else {
        #pragma unroll
        for (int s = 0; s < 4; s++) {
            const float* rp = inputs + (size_t)(rowbase + s * 16 + li) * NFEAT + q * 8;
            #pragma unroll
            for (int kc = 0; kc < 8; kc++) {
                const float4 x0 = *reinterpret_cast<const float4*>(rp + kc * 32);
                const float4 x1 = *reinterpret_cast<const float4*>(rp + kc * 32 + 4);
                bf16x8 a;
                a[0] = bfb(x0.x); a[1] = bfb(x0.y); a[2] = bfb(x0.z); a[3] = bfb(x0.w);
                a[4] = bfb(x1.x); a[5] = bfb(x1.y); a[6] = bfb(x1.z); a[7] = bfb(x1.w);
                afrag[s][kc] = a;
            }
        }
    }

    float sums[4][4] = {{0.f,0.f,0.f,0.f},{0.f,0.f,0.f,0.f},
                        {0.f,0.f,0.f,0.f},{0.f,0.f,0.f,0.f}};
    char* const lbase = (char*)&ldsb[0][0];

    if constexpr (TB) {
        const int cc0 = tid >> 5;
        const int uo = ((tid & 31) ^ (4 * (cc0 & 7))) * 8;
        const int ldd = wave * 1024;
        const int cA = (cs * NCH32) >> 6;
        const int cB = ((cs + 1) * NCH32) >> 6;
        const int NB = cB - cA;
        const unsigned short* psrc = tb + (size_t)(cA * 32 + cc0) * NFEAT + uo;
        int ob0 = 0, ob1 = 16384, ob2 = 32768;

        #pragma unroll
        for (int k = 0; k < 4; k++)
            gll16(psrc + (size_t)(8 * k) * NFEAT, lbase + ob0 + ldd + k * 4096);
        psrc += (size_t)32 * NFEAT;
        if (NB > 1) {
            #pragma unroll
            for (int k = 0; k < 4; k++)
                gll16(psrc + (size_t)(8 * k) * NFEAT, lbase + ob1 + ldd + k * 4096);
            psrc += (size_t)32 * NFEAT;
        }

        for (int i = 0; i < NB; ++i) {
            if (i + 1 < NB) asm volatile("s_waitcnt vmcnt(4)\n\ts_barrier" ::: "memory");
            else            asm volatile("s_waitcnt vmcnt(0)\n\ts_barrier" ::: "memory");
            if (i + 2 < NB) {
                #pragma unroll
                for (int k = 0; k < 4; k++)
                    gll16(psrc + (size_t)(8 * k) * NFEAT, lbase + ob2 + ldd + k * 4096);
                psrc += (size_t)32 * NFEAT;
            }
            #pragma unroll
            for (int h = 0; h < 2; h++) {
                const int cc = h * 16 + li;
                bf16x8 bfr[8];
                #pragma unroll
                for (int kc = 0; kc < 8; kc++) {
                    const int slot = cc * 32 + ((q + 4 * kc) ^ xorli);
                    bfr[kc] = *reinterpret_cast<const bf16x8*>(lbase + ob0 + slot * 16);
                }
                f32x4 acc[4] = {{0.f,0.f,0.f,0.f},{0.f,0.f,0.f,0.f},
                                {0.f,0.f,0.f,0.f},{0.f,0.f,0.f,0.f}};
                __builtin_amdgcn_s_setprio(1);
                #pragma unroll
                for (int kc = 0; kc < 8; kc++) {
                    acc[0] = __builtin_amdgcn_mfma_f32_16x16x32_bf16(afrag[0][kc], bfr[kc], acc[0], 0, 0, 0);
                    acc[1] = __builtin_amdgcn_mfma_f32_16x16x32_bf16(afrag[1][kc], bfr[kc], acc[1], 0, 0, 0);
                    acc[2] = __builtin_amdgcn_mfma_f32_16x16x32_bf16(afrag[2][kc], bfr[kc], acc[2], 0, 0, 0);
                    acc[3] = __builtin_amdgcn_mfma_f32_16x16x32_bf16(afrag[3][kc], bfr[kc], acc[3], 0, 0, 0);
                }
                __builtin_amdgcn_s_setprio(0);
                #pragma unroll
                for (int s = 0; s < 4; s++)
                    #pragma unroll
                    for (int r = 0; r < 4; r++)
                        sums[s][r] += EXP2(S2F * acc[s][r] - S2F);
            }
            const int t = ob0; ob0 = ob1; ob1 = ob2; ob2 = t;
        }
    } else {
        short* fb = (short*)lbase;
        const int s0 = tid, s1 = tid + 256;
        const int cc0 = s0 >> 5, cc1 = s1 >> 5;
        const int uo0 = ((s0 & 31) ^ (4 * (cc0 & 7))) * 8;
        const int uo1 = ((s1 & 31) ^ (4 * (cc1 & 7))) * 8;
        const int cA = (cs * NCHUNKS) >> 6;
        const int cB = ((cs + 1) * NCHUNKS) >> 6;
        {
            int n0 = cA * 16 + cc0; n0 = n0 < (NCLS - 1) ? n0 : (NCLS - 1);
            int n1 = cA * 16 + cc1; n1 = n1 < (NCLS - 1) ? n1 : (NCLS - 1);
            const float* r0 = ((n0 < NPIDS) ? lut + (size_t)n0 * NFEAT
                                            : cq + (size_t)(n0 - NPIDS) * NFEAT) + uo0;
            const float* r1 = ((n1 < NPIDS) ? lut + (size_t)n1 * NFEAT
                                            : cq + (size_t)(n1 - NPIDS) * NFEAT) + uo1;
            const float4 a0 = *reinterpret_cast<const float4*>(r0);
            const float4 a1 = *reinterpret_cast<const float4*>(r0 + 4);
            const float4 b0 = *reinterpret_cast<const float4*>(r1);
            const float4 b1 = *reinterpret_cast<const float4*>(r1 + 4);
            bf16x8 v0, v1;
            v0[0]=bfb(a0.x); v0[1]=bfb(a0.y); v0[2]=bfb(a0.z); v0[3]=bfb(a0.w);
            v0[4]=bfb(a1.x); v0[5]=bfb(a1.y); v0[6]=bfb(a1.z); v0[7]=bfb(a1.w);
            v1[0]=bfb(b0.x); v1[1]=bfb(b0.y); v1[2]=bfb(b0.z); v1[3]=bfb(b0.w);
            v1[4]=bfb(b1.x); v1[5]=bfb(b1.y); v1[6]=bfb(b1.z); v1[7]=bfb(b1.w);
            *reinterpret_cast<bf16x8*>(&fb[s0 * 8]) = v0;
            *reinterpret_cast<bf16x8*>(&fb[s1 * 8]) = v1;
        }
        __syncthreads();
        int cur = 0;
        for (int ci = cA; ci < cB; ++ci) {
            const bool pf = (ci + 1 < cB);
            float4 f0a, f0b, f1a, f1b;
            if (pf) {
                int n0 = (ci + 1) * 16 + cc0; n0 = n0 < (NCLS - 1) ? n0 : (NCLS - 1);
                int n1 = (ci + 1) * 16 + cc1; n1 = n1 < (NCLS - 1) ? n1 : (NCLS - 1);
                const float* r0 = ((n0 < NPIDS) ? lut + (size_t)n0 * NFEAT
                                                : cq + (size_t)(n0 - NPIDS) * NFEAT) + uo0;
                const float* r1 = ((n1 < NPIDS) ? lut + (size_t)n1 * NFEAT
                                                : cq + (size_t)(n1 - NPIDS) * NFEAT) + uo1;
                f0a = *reinterpret_cast<const float4*>(r0);
                f0b = *reinterpret_cast<const float4*>(r0 + 4);
                f1a = *reinterpret_cast<const float4*>(r1);
                f1b = *reinterpret_cast<const float4*>(r1 + 4);
            }
            f32x4 acc[4] = {{0.f,0.f,0.f,0.f},{0.f,0.f,0.f,0.f},
                            {0.f,0.f,0.f,0.f},{0.f,0.f,0.f,0.f}};
            #pragma unroll
            for (int kc = 0; kc < 8; kc++) {
                const int slot = li * 32 + ((q + 4 * kc) ^ xorli);
                const bf16x8 b = *reinterpret_cast<const bf16x8*>(&fb[cur * 4096 + slot * 8]);
                acc[0] = __builtin_amdgcn_mfma_f32_16x16x32_bf16(afrag[0][kc], b, acc[0], 0, 0, 0);
                acc[1] = __builtin_amdgcn_mfma_f32_16x16x32_bf16(afrag[1][kc], b, acc[1], 0, 0, 0);
                acc[2] = __builtin_amdgcn_mfma_f32_16x16x32_bf16(afrag[2][kc], b, acc[2], 0, 0, 0);
                acc[3] = __builtin_amdgcn_mfma_f32_16x16x32_bf16(afrag[3][kc], b, acc[3], 0, 0, 0);
            }
            const float valid = ((ci * 16 + li) < NCLS) ? 1.0f : 0.0f;
            #pragma unroll
            for (int s = 0; s < 4; s++)
                #pragma unroll
                for (int r = 0; r < 4; r++)
                    sums[s][r] += valid * EXP2(S2F * (acc[s][r] - 1.0f));
            if (pf) {
                bf16x8 p0, p1;
                p0[0]=bfb(f0a.x); p0[1]=bfb(f0a.y); p0[2]=bfb(f0a.z); p0[3]=bfb(f0a.w);
                p0[4]=bfb(f0b.x); p0[5]=bfb(f0b.y); p0[6]=bfb(f0b.z); p0[7]=bfb(f0b.w);
                p1[0]=bfb(f1a.x); p1[1]=bfb(f1a.y); p1[2]=bfb(f1a.z); p1[3]=bfb(f1a.w);
                p1[4]=bfb(f1b.x); p1[5]=bfb(f1b.y); p1[6]=bfb(f1b.z); p1[7]=bfb(f1b.w);
                *reinterpret_cast<bf16x8*>(&fb[(cur ^ 1) * 4096 + s0 * 8]) = p0;
                *reinterpret_cast<bf16x8*>(&fb[(cur ^ 1) * 4096 + s1 * 8]) = p1;
            }
            __syncthreads();
            cur ^= 1;
        }
    }

    #pragma unroll
    for (int s = 0; s < 4; s++)
        #pragma unroll
        for (int r = 0; r < 4; r++) {
            float v = sums[s][r];
            v += __shfl_xor(v, 1); v += __shfl_xor(v, 2);
            v += __shfl_xor(v, 4); v += __shfl_xor(v, 8);
            sums[s][r] = v;
        }
    if (li == 0) {
        #pragma unroll
        for (int s = 0; s < 4; s++)
            #pragma unroll
            for (int r = 0; r < 4; r++)
                atomicAdd(&S[rowbase + s * 16 + q * 4 + r], sums[s][r]);
    }
}

__global__ __launch_bounds__(256) void focal_final(const float* __restrict__ inputs,
                                                   const float* __restrict__ lut,
                                                   const int* __restrict__ lab,
                                                   const float* __restrict__ S,
                                                   float* __restrict__ loss_acc,
                                                   unsigned int* __restrict__ cnt,
                                                   float* __restrict__ f) {
    const int wave = threadIdx.x >> 6;
    const int lane = threadIdx.x & 63;
    const int row = blockIdx.x * 4 + wave;
    const int label = lab[row];
    const bool valid = (label >= 0 && label < NPIDS);
    const int lr = valid ? label : 0;
    const float4 a = *reinterpret_cast<const float4*>(inputs + (size_t)row * NFEAT + lane * 4);
    const float4 b = *reinterpret_cast<const float4*>(lut + (size_t)lr * NFEAT + lane * 4);
    float v = a.x * b.x + a.y * b.y + a.z * b.z + a.w * b.w;
    #pragma unroll
    for (int m = 1; m < 64; m <<= 1) v += __shfl_xor(v, m);

    __shared__ float red[4];
    if (lane == 0) {
        float fo = 0.0f;
        if (valid) {
            const float l2 = v * S2F;
            const float lse2 = S2F + log2f(S[row]);
            float ce = fmaxf((lse2 - l2) * LN2F, 0.0f);
            const float pt = EXP2(l2 - lse2);
            const float om = 1.0f - pt;
            fo = om * om * ce;
        }
        red[wave] = fo;
    }
    __syncthreads();
    if (threadIdx.x == 0) {
        atomicAdd(loss_acc, red[0] + red[1] + red[2] + red[3]);
        __threadfence();
        const unsigned done = atomicAdd(cnt, 1u) + 1u;
        if (done == gridDim.x) {
            const float tot = atomicAdd(loss_acc, 0.0f);
            f[0] = tot * (1.0f / NROIS);
        }
    }
}

extern "C" void kernel_launch(void* const* d_in, const int* in_sizes, int n_in,
                              void* d_out, int out_size, void* d_ws, size_t ws_size,
                              hipStream_t stream) {
    const float* inputs = (const float*)d_in[0];
    const float* lut    = (const float*)d_in[1];
    const float* cq     = (const float*)d_in[2];
    const int*   cand0  = (const int*)d_in[3];     // targets
    const int*   cand1  = (const int*)((n_in > 4) ? d_in[4] : d_in[3]);
    float* f = (float*)d_out;

    const size_t TBB = (size_t)NCLSP * NFEAT * 2;  // 28.46 MB padded bf16 table
    const size_t ABB = (size_t)NROIS * NFEAT * 2;  // 1 MB bf16 A
    char* ws = (char*)d_ws;
    const bool useTB = ws_size >= TBB + ABB + 32768;

    unsigned short* tb = useTB ? (unsigned short*)ws : nullptr;
    unsigned short* ab = useTB ? (unsigned short*)(ws + TBB) : nullptr;
    float* S = useTB ? (float*)(ws + TBB + ABB) : (float*)ws;
    float* loss_acc    = S + NROIS;                           // S[2048]
    unsigned int* cnt  = (unsigned int*)(S + NROIS + 1);      // S[2049]
    int* lab           = (int*)(S + NROIS + 8);               // S[2056..]

    if (useTB) {
        void* kargs[] = {(void*)&inputs, (void*)&lut, (void*)&cq, (void*)&cand0,
                         (void*)&cand1, (void*)&tb, (void*)&ab, (void*)&lab,
                         (void*)&S, (void*)&loss_acc, (void*)&cnt, (void*)&f};
        const hipError_t ce = hipLaunchCooperativeKernel(
            (const void*)mega, dim3(512), dim3(256), kargs, 0, stream);
        if (ce == hipSuccess) return;
        // cooperative rejected (e.g. graph capture): fall through to 3-kernel path
    }

    preprocess<<<useTB ? 4096 : 512, 256, 0, stream>>>(inputs, lut, cq, cand0, cand1,
                                                       tb, ab, lab, S, f, useTB ? 1 : 0);
    if (useTB) main_gemm4<true><<<512, 256, 0, stream>>>(inputs, tb, ab, lut, cq, S);
    else       main_gemm4<false><<<512, 256, 0, stream>>>(inputs, tb, ab, lut, cq, S);
    focal_final<<<512, 256, 0, stream>>>(inputs, lut, lab, S, loss_acc, cnt, f);
}

// Round 6
// 171.560 us; speedup vs baseline: 1.8363x; 1.8363x over previous
//
#include <hip/hip_runtime.h>
#include <hip/hip_bf16.h>

// LOIMLoss on MI355X (gfx950) — R18: deferred-exp pipeline in the R14 gemm.
// R17 FAILED (315us): cooperative mega-kernel capped phase0 at 2 blocks/CU
// (~590 GB/s streaming) and revealed ~97us FIXED harness overhead (graph +
// reset memsets) — the "tail" is not addressable; preprocess+focal ~13us.
// All wins must come from the gemm (62us). Reverted to R14 3-kernel path.
// R14 accounting: 5511 cyc/chunk-period/CU; MFMA demand 2483 (45%); the
// 32 exp2/chunk epilogue (~1000-1500 cyc) is SERIAL after its own MFMAs.
// R18: two static acc sets (accX/accY). Sub-chunk t MFMAs into one set while
// exp-accumulating the set from t-1 (independent -> scheduler hides it under
// lgkm waits + MFMA shadow; T15 pattern). Prologue accY=0 contributes
// 16 x 2^-43.3 ~ 2e-12 (harmless, same as zero-pad rows); epilogue exps the
// last accY. Staging/swizzle/vmcnt/setprio BYTE-IDENTICAL to R14.
//
// Output model (R11, absmax 0.0): d_out f32[out]; [0]=loss, [1..524289)=inputs
// copy, [524289..)=label bf16-RNE upcast. d_in[0..2] f32.

#define NFEAT 256
#define NROIS 2048
#define NPIDS 5554
#define NCLS 55554            // NPIDS + 50000
#define NCHUNKS 3473          // ceil(NCLS/16)  (non-TB fallback granularity)
#define NCH32 1737            // ceil(NCLS/32)  (TB path granularity)
#define NCLSP (NCH32 * 32)    // 55584: rows [NCLS..NCLSP) zeroed in tb
#define S2F 43.280851226668906f   // 30 * log2(e)
#define LN2F 0.6931471805599453f
#define LOFF 524289

typedef float f32x4 __attribute__((ext_vector_type(4)));
typedef short bf16x8 __attribute__((ext_vector_type(8)));
typedef unsigned short u16x8 __attribute__((ext_vector_type(8)));

#if __has_builtin(__builtin_amdgcn_exp2f)
#define EXP2(x) __builtin_amdgcn_exp2f(x)
#else
#define EXP2(x) exp2f(x)
#endif

__device__ __forceinline__ short bfb(float x) {
    return __builtin_bit_cast(short, __float2bfloat16(x));   // RNE
}

// 16B global->LDS direct (dest = wave-uniform base + lane*16, src per-lane).
__device__ __forceinline__ void gll16(const void* g, void* l) {
    __builtin_amdgcn_global_load_lds(
        (const __attribute__((address_space(1))) void*)g,
        (__attribute__((address_space(3))) void*)l, 16, 0, 0);
}

// ---- kernel A: fused prep + table cvt (+zero pad) + inputs copy + ab cvt ----
__global__ __launch_bounds__(256) void preprocess(
        const float* __restrict__ inputs, const float* __restrict__ lut,
        const float* __restrict__ cq, const int* __restrict__ cand0,
        const int* __restrict__ cand1, unsigned short* __restrict__ tb,
        unsigned short* __restrict__ ab, int* __restrict__ lab,
        float* __restrict__ S, float* __restrict__ f, const int useTB) {
    const int tid = threadIdx.x;
    const int bx = blockIdx.x;

    if (bx == 0) {
        __shared__ int smode;
        __shared__ const int* sT;
        if (tid == 0) {
            const int* T = cand0;
            const unsigned u0 = (unsigned)cand0[0];
            const float f0 = __builtin_bit_cast(float, cand0[0]);
            const bool oki = (u0 >= 1u && u0 <= 6000u);
            const bool okf = (f0 >= 1.0f && f0 <= 6000.0f);
            if (!oki && !okf) T = cand1;
            int mode = 0;                      // 0=int32, 1=int64(LE), 2=f32
            const unsigned tu0 = (unsigned)T[0];
            const float tf0 = __builtin_bit_cast(float, T[0]);
            if (tu0 >= 1u && tu0 <= 6000u) mode = ((T[1] | T[3] | T[5] | T[7]) == 0) ? 1 : 0;
            else if (tf0 >= 1.0f && tf0 <= 6000.0f) mode = 2;
            smode = mode; sT = T;
        }
        __syncthreads();
        const int mode = smode;
        const int* T = sT;
        for (int j = tid; j < NROIS; j += 256) {
            int tv;
            if (mode == 1)      tv = T[2 * j];
            else if (mode == 2) tv = (int)__builtin_bit_cast(float, T[j]);
            else                tv = T[j];
            const int lv = tv - 1;
            lab[j] = lv;
            f[LOFF + j] = __bfloat162float(__float2bfloat16((float)lv));
        }
        for (int j = tid; j < NROIS + 8; j += 256) S[j] = 0.0f;  // S, loss, cnt
    }

    if (bx < 512) {
        const int i = bx * 256 + tid;                 // 131072 float4 units
        const float4 v = *reinterpret_cast<const float4*>(inputs + (size_t)i * 4);
        float* o = f + 1 + (size_t)i * 4;             // f+1 unaligned: scalar stores
        o[0] = v.x; o[1] = v.y; o[2] = v.z; o[3] = v.w;
        if (useTB) {
            ushort4 u;
            u.x = (unsigned short)bfb(v.x); u.y = (unsigned short)bfb(v.y);
            u.z = (unsigned short)bfb(v.z); u.w = (unsigned short)bfb(v.w);
            *reinterpret_cast<ushort4*>(ab + (size_t)i * 4) = u;
        }
    }

    if (useTB) {
        const size_t LUTN = (size_t)NPIDS * NFEAT;    // divisible by 8
        const size_t TOT  = (size_t)NCLS * NFEAT;     // divisible by 8
        const size_t TOTP = (size_t)NCLSP * NFEAT;
        const size_t stride = (size_t)gridDim.x * 256 * 8;
        for (size_t e = ((size_t)bx * 256 + tid) * 8; e < TOTP; e += stride) {
            u16x8 o = {0, 0, 0, 0, 0, 0, 0, 0};
            if (e < TOT) {
                const float* sp = (e < LUTN) ? (lut + e) : (cq + (e - LUTN));
                const float4 a = *reinterpret_cast<const float4*>(sp);
                const float4 b = *reinterpret_cast<const float4*>(sp + 4);
                o[0] = (unsigned short)bfb(a.x); o[1] = (unsigned short)bfb(a.y);
                o[2] = (unsigned short)bfb(a.z); o[3] = (unsigned short)bfb(a.w);
                o[4] = (unsigned short)bfb(b.x); o[5] = (unsigned short)bfb(b.y);
                o[6] = (unsigned short)bfb(b.z); o[7] = (unsigned short)bfb(b.w);
            }
            *reinterpret_cast<u16x8*>(tb + e) = o;
        }
    }
}

// ---- kernel B: main GEMM v7 -------------------------------------------------
// grid 512 = 8 row-groups x 64 class-slices (bx%8 = cs%8 -> XCD-local B slice
// ~3.56 MB fits 4 MB L2). 4 waves x 64 rows; A resident bf16 frags (128 regs).
// TB path: 32-class chunk (16 KB) staged by 4 gll16/thread into 3 rotating
// LDS buffers; per-chunk sync = "s_waitcnt vmcnt(4); s_barrier" (next chunk's
// 4 loads stay in flight; only vmem in-loop = gll16 -> counts exact). R14
// swizzle: slot cc*32+p holds global unit p^(4*(cc&7)); read
// slot cc*32+((q+4kc)^(4*(li&7))) returns unit q+4kc.
// R18 pipeline: sub-chunk h MFMAs into accX (h=0) / accY (h=1) while the exp
// epilogue of the PREVIOUS sub-chunk's set runs (independent -> hidden).
template <bool TB>
__global__ __launch_bounds__(256, 2) void main_gemm7(const float* __restrict__ inputs,
                                                     const unsigned short* __restrict__ tb,
                                                     const unsigned short* __restrict__ ab,
                                                     const float* __restrict__ lut,
                                                     const float* __restrict__ cq,
                                                     float* __restrict__ S) {
    __shared__ short ldsb[3][8192];               // 3 x 16 KB (fallback uses 2x8KB)
    const int tid = threadIdx.x;
    const int lane = tid & 63;
    const int wave = tid >> 6;
    const int cs = blockIdx.x & 63;
    const int rg = blockIdx.x >> 6;
    const int rowbase = rg * 256 + wave * 64;
    const int li = lane & 15;
    const int q = lane >> 4;
    const int xorli = 4 * (li & 7);
    char* const lbase = (char*)&ldsb[0][0];

    float sums[4][4] = {{0.f,0.f,0.f,0.f},{0.f,0.f,0.f,0.f},
                        {0.f,0.f,0.f,0.f},{0.f,0.f,0.f,0.f}};

    if constexpr (TB) {
        // A fragments: lane holds A[m=li][k=q*8+kc*32..+7] for 4 row-subtiles
        bf16x8 afrag[4][8];
        #pragma unroll
        for (int s = 0; s < 4; s++) {
            const unsigned short* rp = ab + (size_t)(rowbase + s * 16 + li) * NFEAT + q * 8;
            #pragma unroll
            for (int kc = 0; kc < 8; kc++)
                afrag[s][kc] = *reinterpret_cast<const bf16x8*>(rp + kc * 32);
        }

        const int cc0 = tid >> 5;
        const int uo = ((tid & 31) ^ (4 * (cc0 & 7))) * 8;
        const int ldd = wave * 1024;             // + k*4096, HW adds lane*16
        const int cA = (cs * NCH32) >> 6;
        const int cB = ((cs + 1) * NCH32) >> 6;
        const int NB = cB - cA;
        const unsigned short* psrc = tb + (size_t)(cA * 32 + cc0) * NFEAT + uo;
        int ob0 = 0, ob1 = 16384, ob2 = 32768;

        // prologue: issue chunks cA, cA+1
        #pragma unroll
        for (int k = 0; k < 4; k++)
            gll16(psrc + (size_t)(8 * k) * NFEAT, lbase + ob0 + ldd + k * 4096);
        psrc += (size_t)32 * NFEAT;
        if (NB > 1) {
            #pragma unroll
            for (int k = 0; k < 4; k++)
                gll16(psrc + (size_t)(8 * k) * NFEAT, lbase + ob1 + ldd + k * 4096);
            psrc += (size_t)32 * NFEAT;
        }

        // two static acc sets (rule #20: named, never runtime-indexed).
        f32x4 accX[4], accY[4];
        #pragma unroll
        for (int s = 0; s < 4; s++) accY[s] = (f32x4){0.f, 0.f, 0.f, 0.f};
        // exp(accY=0) in the first sub-chunk adds 2^-43.3 ~ 1e-13/elem: harmless.

        for (int i = 0; i < NB; ++i) {
            if (i + 1 < NB) asm volatile("s_waitcnt vmcnt(4)\n\ts_barrier" ::: "memory");
            else            asm volatile("s_waitcnt vmcnt(0)\n\ts_barrier" ::: "memory");
            if (i + 2 < NB) {
                #pragma unroll
                for (int k = 0; k < 4; k++)
                    gll16(psrc + (size_t)(8 * k) * NFEAT, lbase + ob2 + ldd + k * 4096);
                psrc += (size_t)32 * NFEAT;
            }
            // ---- sub-chunk h=0: MFMA -> accX, exp(accY from previous sub ----
            {
                const int cc = li;                       // h=0
                bf16x8 bfr[8];
                #pragma unroll
                for (int kc = 0; kc < 8; kc++) {
                    const int slot = cc * 32 + ((q + 4 * kc) ^ xorli);
                    bfr[kc] = *reinterpret_cast<const bf16x8*>(lbase + ob0 + slot * 16);
                }
                #pragma unroll
                for (int s = 0; s < 4; s++) accX[s] = (f32x4){0.f, 0.f, 0.f, 0.f};
                // deferred exp of accY (independent of bfr/MFMA -> fills waits)
                #pragma unroll
                for (int s = 0; s < 4; s++)
                    #pragma unroll
                    for (int r = 0; r < 4; r++)
                        sums[s][r] += EXP2(S2F * accY[s][r] - S2F);
                __builtin_amdgcn_s_setprio(1);
                #pragma unroll
                for (int kc = 0; kc < 8; kc++) {
                    accX[0] = __builtin_amdgcn_mfma_f32_16x16x32_bf16(afrag[0][kc], bfr[kc], accX[0], 0, 0, 0);
                    accX[1] = __builtin_amdgcn_mfma_f32_16x16x32_bf16(afrag[1][kc], bfr[kc], accX[1], 0, 0, 0);
                    accX[2] = __builtin_amdgcn_mfma_f32_16x16x32_bf16(afrag[2][kc], bfr[kc], accX[2], 0, 0, 0);
                    accX[3] = __builtin_amdgcn_mfma_f32_16x16x32_bf16(afrag[3][kc], bfr[kc], accX[3], 0, 0, 0);
                }
                __builtin_amdgcn_s_setprio(0);
            }
            // ---- sub-chunk h=1: MFMA -> accY, exp(accX) ----
            {
                const int cc = 16 + li;                  // h=1
                bf16x8 bfr[8];
                #pragma unroll
                for (int kc = 0; kc < 8; kc++) {
                    const int slot = cc * 32 + ((q + 4 * kc) ^ xorli);
                    bfr[kc] = *reinterpret_cast<const bf16x8*>(lbase + ob0 + slot * 16);
                }
                #pragma unroll
                for (int s = 0; s < 4; s++) accY[s] = (f32x4){0.f, 0.f, 0.f, 0.f};
                #pragma unroll
                for (int s = 0; s < 4; s++)
                    #pragma unroll
                    for (int r = 0; r < 4; r++)
                        sums[s][r] += EXP2(S2F * accX[s][r] - S2F);
                __builtin_amdgcn_s_setprio(1);
                #pragma unroll
                for (int kc = 0; kc < 8; kc++) {
                    accY[0] = __builtin_amdgcn_mfma_f32_16x16x32_bf16(afrag[0][kc], bfr[kc], accY[0], 0, 0, 0);
                    accY[1] = __builtin_amdgcn_mfma_f32_16x16x32_bf16(afrag[1][kc], bfr[kc], accY[1], 0, 0, 0);
                    accY[2] = __builtin_amdgcn_mfma_f32_16x16x32_bf16(afrag[2][kc], bfr[kc], accY[2], 0, 0, 0);
                    accY[3] = __builtin_amdgcn_mfma_f32_16x16x32_bf16(afrag[3][kc], bfr[kc], accY[3], 0, 0, 0);
                }
                __builtin_amdgcn_s_setprio(0);
            }
            const int t = ob0; ob0 = ob1; ob1 = ob2; ob2 = t;
        }
        // epilogue: last sub-chunk's accY still pending
        #pragma unroll
        for (int s = 0; s < 4; s++)
            #pragma unroll
            for (int r = 0; r < 4; r++)
                sums[s][r] += EXP2(S2F * accY[s][r] - S2F);
    } else {
        // fallback (no ws table): R14 reg-staged double-buffer loop (proven).
        bf16x8 afrag[4][8];
        #pragma unroll
        for (int s = 0; s < 4; s++) {
            const float* rp = inputs + (size_t)(rowbase + s * 16 + li) * NFEAT + q * 8;
            #pragma unroll
            for (int kc = 0; kc < 8; kc++) {
                const float4 x0 = *reinterpret_cast<const float4*>(rp + kc * 32);
                const float4 x1 = *reinterpret_cast<const float4*>(rp + kc * 32 + 4);
                bf16x8 a;
                a[0] = bfb(x0.x); a[1] = bfb(x0.y); a[2] = bfb(x0.z); a[3] = bfb(x0.w);
                a[4] = bfb(x1.x); a[5] = bfb(x1.y); a[6] = bfb(x1.z); a[7] = bfb(x1.w);
                afrag[s][kc] = a;
            }
        }
        short* fb = (short*)lbase;
        const int s0 = tid, s1 = tid + 256;
        const int cc0 = s0 >> 5, cc1 = s1 >> 5;
        const int uo0 = ((s0 & 31) ^ (4 * (cc0 & 7))) * 8;
        const int uo1 = ((s1 & 31) ^ (4 * (cc1 & 7))) * 8;
        const int cA = (cs * NCHUNKS) >> 6;
        const int cB = ((cs + 1) * NCHUNKS) >> 6;
        {
            int n0 = cA * 16 + cc0; n0 = n0 < (NCLS - 1) ? n0 : (NCLS - 1);
            int n1 = cA * 16 + cc1; n1 = n1 < (NCLS - 1) ? n1 : (NCLS - 1);
            const float* r0 = ((n0 < NPIDS) ? lut + (size_t)n0 * NFEAT
                                            : cq + (size_t)(n0 - NPIDS) * NFEAT) + uo0;
            const float* r1 = ((n1 < NPIDS) ? lut + (size_t)n1 * NFEAT
                                            : cq + (size_t)(n1 - NPIDS) * NFEAT) + uo1;
            const float4 a0 = *reinterpret_cast<const float4*>(r0);
            const float4 a1 = *reinterpret_cast<const float4*>(r0 + 4);
            const float4 b0 = *reinterpret_cast<const float4*>(r1);
            const float4 b1 = *reinterpret_cast<const float4*>(r1 + 4);
            bf16x8 v0, v1;
            v0[0]=bfb(a0.x); v0[1]=bfb(a0.y); v0[2]=bfb(a0.z); v0[3]=bfb(a0.w);
            v0[4]=bfb(a1.x); v0[5]=bfb(a1.y); v0[6]=bfb(a1.z); v0[7]=bfb(a1.w);
            v1[0]=bfb(b0.x); v1[1]=bfb(b0.y); v1[2]=bfb(b0.z); v1[3]=bfb(b0.w);
            v1[4]=bfb(b1.x); v1[5]=bfb(b1.y); v1[6]=bfb(b1.z); v1[7]=bfb(b1.w);
            *reinterpret_cast<bf16x8*>(&fb[s0 * 8]) = v0;
            *reinterpret_cast<bf16x8*>(&fb[s1 * 8]) = v1;
        }
        __syncthreads();
        int cur = 0;
        for (int ci = cA; ci < cB; ++ci) {
            const bool pf = (ci + 1 < cB);
            float4 f0a, f0b, f1a, f1b;
            if (pf) {
                int n0 = (ci + 1) * 16 + cc0; n0 = n0 < (NCLS - 1) ? n0 : (NCLS - 1);
                int n1 = (ci + 1) * 16 + cc1; n1 = n1 < (NCLS - 1) ? n1 : (NCLS - 1);
                const float* r0 = ((n0 < NPIDS) ? lut + (size_t)n0 * NFEAT
                                                : cq + (size_t)(n0 - NPIDS) * NFEAT) + uo0;
                const float* r1 = ((n1 < NPIDS) ? lut + (size_t)n1 * NFEAT
                                                : cq + (size_t)(n1 - NPIDS) * NFEAT) + uo1;
                f0a = *reinterpret_cast<const float4*>(r0);
                f0b = *reinterpret_cast<const float4*>(r0 + 4);
                f1a = *reinterpret_cast<const float4*>(r1);
                f1b = *reinterpret_cast<const float4*>(r1 + 4);
            }
            f32x4 acc[4] = {{0.f,0.f,0.f,0.f},{0.f,0.f,0.f,0.f},
                            {0.f,0.f,0.f,0.f},{0.f,0.f,0.f,0.f}};
            #pragma unroll
            for (int kc = 0; kc < 8; kc++) {
                const int slot = li * 32 + ((q + 4 * kc) ^ xorli);
                const bf16x8 b = *reinterpret_cast<const bf16x8*>(&fb[cur * 4096 + slot * 8]);
                acc[0] = __builtin_amdgcn_mfma_f32_16x16x32_bf16(afrag[0][kc], b, acc[0], 0, 0, 0);
                acc[1] = __builtin_amdgcn_mfma_f32_16x16x32_bf16(afrag[1][kc], b, acc[1], 0, 0, 0);
                acc[2] = __builtin_amdgcn_mfma_f32_16x16x32_bf16(afrag[2][kc], b, acc[2], 0, 0, 0);
                acc[3] = __builtin_amdgcn_mfma_f32_16x16x32_bf16(afrag[3][kc], b, acc[3], 0, 0, 0);
            }
            const float valid = ((ci * 16 + li) < NCLS) ? 1.0f : 0.0f;
            #pragma unroll
            for (int s = 0; s < 4; s++)
                #pragma unroll
                for (int r = 0; r < 4; r++)
                    sums[s][r] += valid * EXP2(S2F * (acc[s][r] - 1.0f));
            if (pf) {
                bf16x8 p0, p1;
                p0[0]=bfb(f0a.x); p0[1]=bfb(f0a.y); p0[2]=bfb(f0a.z); p0[3]=bfb(f0a.w);
                p0[4]=bfb(f0b.x); p0[5]=bfb(f0b.y); p0[6]=bfb(f0b.z); p0[7]=bfb(f0b.w);
                p1[0]=bfb(f1a.x); p1[1]=bfb(f1a.y); p1[2]=bfb(f1a.z); p1[3]=bfb(f1a.w);
                p1[4]=bfb(f1b.x); p1[5]=bfb(f1b.y); p1[6]=bfb(f1b.z); p1[7]=bfb(f1b.w);
                *reinterpret_cast<bf16x8*>(&fb[(cur ^ 1) * 4096 + s0 * 8]) = p0;
                *reinterpret_cast<bf16x8*>(&fb[(cur ^ 1) * 4096 + s1 * 8]) = p1;
            }
            __syncthreads();
            cur ^= 1;
        }
    }

    // reduce over the 16 class-lanes, atomically add per-row sum-exp
    #pragma unroll
    for (int s = 0; s < 4; s++)
        #pragma unroll
        for (int r = 0; r < 4; r++) {
            float v = sums[s][r];
            v += __shfl_xor(v, 1); v += __shfl_xor(v, 2);
            v += __shfl_xor(v, 4); v += __shfl_xor(v, 8);
            sums[s][r] = v;
        }
    if (li == 0) {
        #pragma unroll
        for (int s = 0; s < 4; s++)
            #pragma unroll
            for (int r = 0; r < 4; r++)
                atomicAdd(&S[rowbase + s * 16 + q * 4 + r], sums[s][r]);
    }
}

// ---- kernel C: exact f32 label dot + focal; last block writes loss ---------
__global__ __launch_bounds__(256) void focal_final(const float* __restrict__ inputs,
                                                   const float* __restrict__ lut,
                                                   const int* __restrict__ lab,
                                                   const float* __restrict__ S,
                                                   float* __restrict__ loss_acc,
                                                   unsigned int* __restrict__ cnt,
                                                   float* __restrict__ f) {
    const int wave = threadIdx.x >> 6;
    const int lane = threadIdx.x & 63;
    const int row = blockIdx.x * 4 + wave;
    const int label = lab[row];
    const bool valid = (label >= 0 && label < NPIDS);
    const int lr = valid ? label : 0;
    const float4 a = *reinterpret_cast<const float4*>(inputs + (size_t)row * NFEAT + lane * 4);
    const float4 b = *reinterpret_cast<const float4*>(lut + (size_t)lr * NFEAT + lane * 4);
    float v = a.x * b.x + a.y * b.y + a.z * b.z + a.w * b.w;
    #pragma unroll
    for (int m = 1; m < 64; m <<= 1) v += __shfl_xor(v, m);

    __shared__ float red[4];
    if (lane == 0) {
        float fo = 0.0f;
        if (valid) {
            const float l2 = v * S2F;
            const float lse2 = S2F + log2f(S[row]);
            float ce = fmaxf((lse2 - l2) * LN2F, 0.0f);
            const float pt = EXP2(l2 - lse2);
            const float om = 1.0f - pt;
            fo = om * om * ce;
        }
        red[wave] = fo;
    }
    __syncthreads();
    if (threadIdx.x == 0) {
        atomicAdd(loss_acc, red[0] + red[1] + red[2] + red[3]);
        __threadfence();
        const unsigned done = atomicAdd(cnt, 1u) + 1u;
        if (done == gridDim.x) {                       // last block: write loss
            const float tot = atomicAdd(loss_acc, 0.0f);  // coherent read
            f[0] = tot * (1.0f / NROIS);
        }
    }
}

extern "C" void kernel_launch(void* const* d_in, const int* in_sizes, int n_in,
                              void* d_out, int out_size, void* d_ws, size_t ws_size,
                              hipStream_t stream) {
    const float* inputs = (const float*)d_in[0];
    const float* lut    = (const float*)d_in[1];
    const float* cq     = (const float*)d_in[2];
    const int*   cand0  = (const int*)d_in[3];     // targets
    const int*   cand1  = (const int*)((n_in > 4) ? d_in[4] : d_in[3]);
    float* f = (float*)d_out;

    const size_t TBB = (size_t)NCLSP * NFEAT * 2;  // 28.46 MB padded bf16 table
    const size_t ABB = (size_t)NROIS * NFEAT * 2;  // 1 MB bf16 A
    char* ws = (char*)d_ws;
    const bool useTB = ws_size >= TBB + ABB + 32768;

    unsigned short* tb = useTB ? (unsigned short*)ws : nullptr;
    unsigned short* ab = useTB ? (unsigned short*)(ws + TBB) : nullptr;
    float* S = useTB ? (float*)(ws + TBB + ABB) : (float*)ws;
    float* loss_acc    = S + NROIS;                           // S[2048]
    unsigned int* cnt  = (unsigned int*)(S + NROIS + 1);      // S[2049]
    int* lab           = (int*)(S + NROIS + 8);               // S[2056..]

    preprocess<<<useTB ? 4096 : 512, 256, 0, stream>>>(inputs, lut, cq, cand0, cand1,
                                                       tb, ab, lab, S, f, useTB ? 1 : 0);
    if (useTB) main_gemm7<true><<<512, 256, 0, stream>>>(inputs, tb, ab, lut, cq, S);
    else       main_gemm7<false><<<512, 256, 0, stream>>>(inputs, tb, ab, lut, cq, S);
    focal_final<<<512, 256, 0, stream>>>(inputs, lut, lab, S, loss_acc, cnt, f);
}